// Round 3
// baseline (162.451 us; speedup 1.0000x reference)
//
#include <hip/hip_runtime.h>

#define RAD 8
#define HH 256
#define WW 256
#define NC 12
#define PS (HH*WW)

// XCD-consistent swizzle for 768 blocks.
__device__ __forceinline__ int swz(int b) { return (b & 7) * 96 + (b >> 3); }

// run17: lane l returns sum of x over lanes [l-16, l]  (valid for l >= 16).
// shfl_up returns own value when src lane < 0, which only pollutes lanes < 16.
__device__ __forceinline__ float run17(float x) {
    float s = x + __shfl_up(x, 1, 64);
    s += __shfl_up(s, 2, 64);
    s += __shfl_up(s, 4, 64);
    s += __shfl_up(s, 8, 64);      // now sum of lanes [l-15, l]
    s += __shfl_up(x, 16, 64);     // + lane l-16  -> 17-wide
    return s;
}

// ---------- K0: global sum of |l_a|+eps ----------
__global__ __launch_bounds__(256) void k_reduce(const float* __restrict__ la,
                                                float* __restrict__ partials) {
    int tid = threadIdx.x;
    __shared__ float ls[4];
    const float4* p4 = (const float4*)la;
    int base = blockIdx.x * 2048 + tid;
    float s = 0.f;
    #pragma unroll
    for (int i = 0; i < 8; i++) {
        float4 v = p4[base + i * 256];
        s += (fabsf(v.x) + 1e-12f) + (fabsf(v.y) + 1e-12f) +
             (fabsf(v.z) + 1e-12f) + (fabsf(v.w) + 1e-12f);
    }
    for (int off = 32; off > 0; off >>= 1) s += __shfl_down(s, off, 64);
    int lane = tid & 63, wid = tid >> 6;
    if (lane == 0) ls[wid] = s;
    __syncthreads();
    if (tid == 0) partials[blockIdx.x] = ls[0] + ls[1] + ls[2] + ls[3];
}

// ---------- K1: barrier-free band kernel. One wave64 -> 32x8 patch of mA/mB ----------
// Lane layout: product col = cp*32 - 16 + lane.
// run17 stage 1 -> A/b at col-8 (valid lanes 16..63).
// run17 stage 2 -> mA/mB at col-16 (valid lanes 32..63 = 32 output cols).
__global__ __launch_bounds__(256) void k_band(const float* __restrict__ la,
                                              const float* __restrict__ lx,
                                              const float* __restrict__ ly,
                                              const float* __restrict__ partials,
                                              float* __restrict__ mA,
                                              float* __restrict__ mB) {
    __shared__ float2 ring[4][17][64];   // per-wave private 17-row A/b ring (34816 B)
    int tid = threadIdx.x, lane = tid & 63, wv = tid >> 6;
    int gw  = swz(blockIdx.x) * 4 + wv;          // 0..3071
    int p   = gw >> 8;                           // plane
    int rem = gw & 255;
    int cp  = rem & 7, rb = rem >> 3;
    int i0  = rb << 3;                           // first output row
    int col = (cp << 5) - 16 + lane;             // product column for this lane
    bool vc = (col >= 0) && (col < WW);
    int colc = min(max(col, 0), WW - 1);
    const float* pa = la + p * PS + colc;
    const float* px = lx + p * PS + colc;
    const float* py = ly + p * PS + colc;

    // invS from the 96 per-block partials (wave-local reduce, no barrier)
    float psum = partials[lane] + ((lane < 32) ? partials[lane + 64] : 0.0f);
    #pragma unroll
    for (int off = 32; off > 0; off >>= 1) psum += __shfl_xor(psum, off, 64);
    float invS = 1.0f / psum;

    // stage-1 A/b column for this lane (centered run17 output): cA = col - 8
    int  cA  = col - 8;
    bool vcA = (cA >= 0) && (cA < WW);
    float cxA = (float)(min(cA + RAD, WW - 1) - max(cA - RAD, 0) + 1);
    // stage-2 output column: cM = col - 16  (lanes 32..63 -> cp*32 .. cp*32+31)
    int   cM  = col - 16;
    float cxM = (float)(min(cM + RAD, WW - 1) - max(cM - RAD, 0) + 1);

    float s0 = 0, s1 = 0, s2 = 0, s3 = 0, s4 = 0, s5 = 0;
    auto accum = [&](int r, float sg) {
        float va = 0.f, vx = 0.f, vy = 0.f;
        if (vc) { int o = r * WW; va = pa[o]; vx = px[o]; vy = py[o]; }
        float a  = vc ? (fabsf(va) + 1e-12f) : 0.f;   // exact 0 outside image
        float ax = a * vx, ay = a * vy;
        s0 = fmaf(sg, a, s0); s1 = fmaf(sg, ax, s1); s2 = fmaf(sg, ay, s2);
        s3 = fmaf(sg, a * ax, s3); s4 = fmaf(sg, ax * ax, s4); s5 = fmaf(sg, ax * ay, s5);
    };

    // init vertical window rows [i0-16, i0] (for first mid row m0 = i0-8)
    #pragma unroll 1
    for (int r = i0 - 16; r <= i0; ++r)
        if (r >= 0) accum(r, 1.0f);

    float tA = 0.f, tB = 0.f;
    int slot = 0;                 // ring slot = (m - (i0-8)) mod 17

    auto midrow = [&](int m, bool doOld, bool doInit, bool doOut) {
        if (m > i0 - 8) {
            int ra = m + 8; if (ra < HH) accum(ra, 1.0f);
            int rs = m - 9; if (rs >= 0) accum(rs, -1.0f);
        }
        float h0 = run17(s0), h1 = run17(s1), h2 = run17(s2),
              h3 = run17(s3), h4 = run17(s4), h5 = run17(s5);
        float Av = 0.f, bv = 0.f;
        if (m >= 0 && m < HH) {                    // wave-uniform branch
            float cy = (float)(min(m + RAD, HH - 1) - max(m - RAD, 0) + 1);
            float Nv = cxA * cy, invN = 1.0f / Nv;
            float m_a = h0 * invN, m_ax = h1 * invN, m_ay = h2 * invN;
            float m_tax = h3 * invN * invS;
            float m_a2x2 = h4 * invN, m_a2xy = h5 * invN;
            float tempv = fabsf(m_a2x2 - Nv * m_tax * m_ax);
            float Avt = (m_a2xy - Nv * m_tax * m_ay) / (tempv + 1e-8f);
            float bvt = (m_ay - Avt * m_ax) / m_a;
            if (vcA) { Av = Avt; bv = bvt; }       // discard NaN/garbage lanes
        }
        if (doOld) {                               // subtract A,b of row m-17
            float2 old = ring[wv][slot][lane];
            tA += Av - old.x; tB += bv - old.y;
        }
        float2 cur; cur.x = Av; cur.y = bv;
        ring[wv][slot][lane] = cur;
        if (doInit) {                              // m == i0+8: sum rows [i0-8, i0+8]
            tA = Av; tB = bv;
            #pragma unroll
            for (int k = 0; k < 16; ++k) {
                int sl = slot + 1 + k; if (sl >= 17) sl -= 17;
                float2 v = ring[wv][sl][lane];
                tA += v.x; tB += v.y;
            }
        }
        if (doOut) {
            int o = m - 8;                          // output row, always in [0,255]
            float HtA = run17(tA), HtB = run17(tB);
            float cy2 = (float)(min(o + RAD, HH - 1) - max(o - RAD, 0) + 1);
            float inv2 = 1.0f / (cxM * cy2);
            if (lane >= 32) {
                int off = p * PS + o * WW + cM;
                mA[off] = HtA * inv2;
                mB[off] = HtB * inv2;
            }
        }
        slot = (slot == 16) ? 0 : slot + 1;
    };

    #pragma unroll 1
    for (int m = i0 - 8; m <= i0 + 7; ++m) midrow(m, false, false, false);
    midrow(i0 + 8, false, true, true);
    #pragma unroll 1
    for (int m = i0 + 9; m <= i0 + 15; ++m) midrow(m, true, false, true);
}

// ---------- K2: bilinear upsample + fuse with hr_x (verbatim passing version) ----------
__global__ __launch_bounds__(256) void k_resize(const float* __restrict__ mA,
                                                const float* __restrict__ mB,
                                                const float* __restrict__ hrx,
                                                float* __restrict__ out) {
    int idx = blockIdx.x * 256 + threadIdx.x;   // float4 index
    int p   = idx >> 18;                        // 1024*256 float4 per plane
    int rem = idx & ((1 << 18) - 1);
    int I   = rem >> 8;                         // HR row
    int J4  = (rem & 255) << 2;                 // HR col start
    const float scale = 255.0f / 1023.0f;
    float ysf = (float)I * scale;
    int   y0  = (int)ysf;
    float wy  = ysf - (float)y0;
    int   y1  = min(y0 + 1, HH - 1);
    const float* a0p = mA + p * PS + y0 * WW;
    const float* a1p = mA + p * PS + y1 * WW;
    const float* b0p = mB + p * PS + y0 * WW;
    const float* b1p = mB + p * PS + y1 * WW;
    int xb = (int)((float)J4 * scale);
    int i1 = min(xb + 1, WW - 1);
    int i2 = min(xb + 2, WW - 1);
    float A0a = a0p[xb], A0b = a0p[i1], A0c = a0p[i2];
    float A1a = a1p[xb], A1b = a1p[i1], A1c = a1p[i2];
    float B0a = b0p[xb], B0b = b0p[i1], B0c = b0p[i2];
    float B1a = b1p[xb], B1b = b1p[i1], B1c = b1p[i2];
    float4 h = ((const float4*)hrx)[idx];
    float hv[4] = {h.x, h.y, h.z, h.w};
    float ov[4];
    float omwy = 1.0f - wy;
    #pragma unroll
    for (int k = 0; k < 4; k++) {
        float xsk = (float)(J4 + k) * scale;
        int   x0  = (int)xsk;
        float wx  = xsk - (float)x0;
        bool hisel = (x0 > xb);
        float Alo0 = hisel ? A0b : A0a, Ahi0 = hisel ? A0c : A0b;
        float Alo1 = hisel ? A1b : A1a, Ahi1 = hisel ? A1c : A1b;
        float Blo0 = hisel ? B0b : B0a, Bhi0 = hisel ? B0c : B0b;
        float Blo1 = hisel ? B1b : B1a, Bhi1 = hisel ? B1c : B1b;
        float omwx = 1.0f - wx;
        float Ar0 = Alo0 * omwx + Ahi0 * wx;
        float Ar1 = Alo1 * omwx + Ahi1 * wx;
        float Br0 = Blo0 * omwx + Bhi0 * wx;
        float Br1 = Blo1 * omwx + Bhi1 * wx;
        float Avv = Ar0 * omwy + Ar1 * wy;
        float Bvv = Br0 * omwy + Br1 * wy;
        ov[k] = Avv * hv[k] + Bvv;
    }
    float4 o;
    o.x = ov[0]; o.y = ov[1]; o.z = ov[2]; o.w = ov[3];
    ((float4*)out)[idx] = o;
}

extern "C" void kernel_launch(void* const* d_in, const int* in_sizes, int n_in,
                              void* d_out, int out_size, void* d_ws, size_t ws_size,
                              hipStream_t stream) {
    const float* lr_x = (const float*)d_in[0];
    const float* lr_y = (const float*)d_in[1];
    const float* hr_x = (const float*)d_in[2];
    const float* l_a  = (const float*)d_in[3];
    float* out = (float*)d_out;

    float* ws       = (float*)d_ws;
    float* partials = ws;                 // 96 floats (pad to 256)
    float* mA       = ws + 256;
    float* mB       = mA + NC * PS;

    k_reduce<<<96, 256, 0, stream>>>(l_a, partials);
    k_band  <<<768, 256, 0, stream>>>(l_a, lr_x, lr_y, partials, mA, mB);
    k_resize<<<(NC * 1024 * 1024 / 4) / 256, 256, 0, stream>>>(mA, mB, hr_x, out);
}

// Round 4
// 139.380 us; speedup vs baseline: 1.1655x; 1.1655x over previous
//
#include <hip/hip_runtime.h>

#define RAD 8
#define HH 256
#define WW 256
#define NC 12
#define PS (HH*WW)

#define NA 52       // A/B halo tile (36 center + 8 halo each side)
#define NM 36
#define AP 53       // LDS stride for A/B tile
#define CP 37       // LDS stride for H-boxed / final tiles

__device__ __forceinline__ int swz768(int b) { return (b & 7) * 96 + (b >> 3); }
__device__ __forceinline__ int swz576(int b) { return (b & 7) * 72 + (b >> 3); }

// run17: lane l returns sum of x over lanes [l-16, l] (valid for l >= 16).
__device__ __forceinline__ float run17(float x) {
    float s = x + __shfl_up(x, 1, 64);
    s += __shfl_up(s, 2, 64);
    s += __shfl_up(s, 4, 64);
    s += __shfl_up(s, 8, 64);      // sum of lanes [l-15, l]
    s += __shfl_up(x, 16, 64);     // + lane l-16 -> 17-wide
    return s;
}

// ---------- K0: global sum of |l_a|+eps ----------
__global__ __launch_bounds__(256) void k_reduce(const float* __restrict__ la,
                                                float* __restrict__ partials) {
    int tid = threadIdx.x;
    __shared__ float ls[4];
    const float4* p4 = (const float4*)la;
    int base = blockIdx.x * 2048 + tid;
    float s = 0.f;
    #pragma unroll
    for (int i = 0; i < 8; i++) {
        float4 v = p4[base + i * 256];
        s += (fabsf(v.x) + 1e-12f) + (fabsf(v.y) + 1e-12f) +
             (fabsf(v.z) + 1e-12f) + (fabsf(v.w) + 1e-12f);
    }
    for (int off = 32; off > 0; off >>= 1) s += __shfl_down(s, off, 64);
    int lane = tid & 63, wid = tid >> 6;
    if (lane == 0) ls[wid] = s;
    __syncthreads();
    if (tid == 0) partials[blockIdx.x] = ls[0] + ls[1] + ls[2] + ls[3];
}

// ---------- K1: A,b computed ONCE per LR pixel. Wave = 48-col x 8-row patch ----------
// Lane product col = C0 - 8 + lane; run17 output center cA = C0 - 16 + lane,
// valid for lanes 16..63 -> 48 consecutive output cols [C0, C0+47].
__global__ __launch_bounds__(256) void k_ab(const float* __restrict__ la,
                                            const float* __restrict__ lx,
                                            const float* __restrict__ ly,
                                            const float* __restrict__ partials,
                                            float* __restrict__ Ab,
                                            float* __restrict__ Bb) {
    int tid = threadIdx.x, lane = tid & 63, wv = tid >> 6;
    int gw = swz576(blockIdx.x) * 4 + wv;        // 0..2303
    int p  = gw / 192;
    int r  = gw - p * 192;
    int s  = r >> 5;                             // col strip 0..5
    int bd = r & 31;                             // row band 0..31
    int i0 = bd << 3;                            // first output row
    int C0 = s * 48;
    int col = C0 - 8 + lane;                     // product column
    bool vc = (col >= 0) && (col < WW);
    int colc = min(max(col, 0), WW - 1);
    const float* pa = la + p * PS + colc;
    const float* px = lx + p * PS + colc;
    const float* py = ly + p * PS + colc;

    // invS from the 96 per-block partials (wave-local, no barrier)
    float psum = partials[lane] + ((lane < 32) ? partials[lane + 64] : 0.0f);
    #pragma unroll
    for (int off = 32; off > 0; off >>= 1) psum += __shfl_xor(psum, off, 64);
    float invS = 1.0f / psum;

    int  cA  = C0 - 16 + lane;                   // output center col (>=0 for lane>=16)
    bool vcA = (lane >= 16) && (cA < WW);
    float cxA = (float)(min(cA + RAD, WW - 1) - max(cA - RAD, 0) + 1);

    float s0 = 0, s1 = 0, s2 = 0, s3 = 0, s4 = 0, s5 = 0;
    auto accum = [&](int rr, float sg) {
        float va = 0.f, vx = 0.f, vy = 0.f;
        if (vc) { int o = rr * WW; va = pa[o]; vx = px[o]; vy = py[o]; }
        float a  = vc ? (fabsf(va) + 1e-12f) : 0.f;   // exact 0 outside image
        float ax = a * vx, ay = a * vy;
        s0 = fmaf(sg, a, s0); s1 = fmaf(sg, ax, s1); s2 = fmaf(sg, ay, s2);
        s3 = fmaf(sg, a * ax, s3); s4 = fmaf(sg, ax * ax, s4); s5 = fmaf(sg, ax * ay, s5);
    };

    // warm-up vertical window rows [i0-8, i0+8]
    #pragma unroll
    for (int d = -8; d <= 8; ++d) {
        int rr = i0 + d;
        if (rr >= 0 && rr < HH) accum(rr, 1.0f);
    }

    float* Apl = Ab + p * PS;
    float* Bpl = Bb + p * PS;
    #pragma unroll
    for (int k = 0; k < 8; ++k) {
        int m = i0 + k;                          // always in [0,255]
        if (k > 0) {
            int ra = m + 8; if (ra < HH) accum(ra, 1.0f);
            int rs = m - 9; if (rs >= 0) accum(rs, -1.0f);
        }
        float h0 = run17(s0), h1 = run17(s1), h2 = run17(s2),
              h3 = run17(s3), h4 = run17(s4), h5 = run17(s5);
        float cy = (float)(min(m + RAD, HH - 1) - max(m - RAD, 0) + 1);
        float Nv = cxA * cy, invN = 1.0f / Nv;
        float m_a = h0 * invN, m_ax = h1 * invN, m_ay = h2 * invN;
        float m_tax = h3 * invN * invS;
        float m_a2x2 = h4 * invN, m_a2xy = h5 * invN;
        float tempv = fabsf(m_a2x2 - Nv * m_tax * m_ax);
        float Av = (m_a2xy - Nv * m_tax * m_ay) / (tempv + 1e-8f);
        float bv = (m_ay - Av * m_ax) / m_a;
        if (vcA) {
            int o = m * WW + cA;
            Apl[o] = Av;
            Bpl[o] = bv;
        }
    }
}

// ---------- K2: per-128x128-HR-tile: box(A),box(b)/N in LDS + bilinear resize + fuse ----------
__global__ __launch_bounds__(256) void k_tile(const float* __restrict__ Ab,
                                              const float* __restrict__ Bb,
                                              const float* __restrict__ hrx,
                                              float* __restrict__ out) {
    __shared__ float sA[NA * AP], sB[NA * AP];     // A/B halo tiles
    __shared__ float sHA[NA * CP], sHB[NA * CP];   // H-boxed
    float* mAb = sA;                               // alias: sA dead after phase 2
    float* mBb = sB;

    int tid = threadIdx.x;
    int b  = swz768(blockIdx.x);
    int p  = b >> 6;
    int t  = b & 63;
    int ti = t >> 3, tj = t & 7;
    int I0 = ti << 7, J0 = tj << 7;
    int Lr0 = max(0, (I0 * 255) / 1023 - 1);
    int Lc0 = max(0, (J0 * 255) / 1023 - 1);

    // phase 1: load 52x52 A/B region, zero-padded outside image
    const float* Apl = Ab + p * PS;
    const float* Bpl = Bb + p * PS;
    for (int idx = tid; idx < NA * NA; idx += 256) {
        int r = idx / NA, c = idx - r * NA;
        int gr = Lr0 - 8 + r, gc = Lc0 - 8 + c;
        float av = 0.f, bv = 0.f;
        if (gr >= 0 && gr < HH && gc >= 0 && gc < WW) {
            int o = gr * WW + gc;
            av = Apl[o]; bv = Bpl[o];
        }
        sA[r * AP + c] = av;
        sB[r * AP + c] = bv;
    }
    __syncthreads();

    // phase 2: horizontal 17-box -> sHA/sHB [52][36]
    for (int job = tid; job < 208; job += 256) {
        int row   = job % 52;
        int which = (job / 52) & 1;
        int strip = job / 104;
        const float* rp = (which ? sB : sA) + row * AP;
        float* dst = (which ? sHB : sHA) + row * CP;
        int c0 = strip * 18;
        float sum = 0.f;
        #pragma unroll
        for (int c = 0; c < 17; ++c) sum += rp[c0 + c];
        dst[c0] = sum;
        for (int jc = c0 + 1; jc < c0 + 18; ++jc) {
            sum += rp[jc + 16] - rp[jc - 1];
            dst[jc] = sum;
        }
    }
    __syncthreads();

    // phase 3: vertical 17-box + /N -> mAb/mBb [36][37] (alias over sA/sB)
    for (int job = tid; job < 144; job += 256) {
        int colc  = job % 36;
        int which = (job / 36) & 1;
        int strip = job / 72;
        const float* src = which ? sHB : sHA;
        float* dst = which ? mBb : mAb;
        int gjC = Lc0 + colc;
        float cxw = (float)(min(gjC + RAD, WW - 1) - max(gjC - RAD, 0) + 1);
        int r0 = strip * 18;
        float sum = 0.f;
        #pragma unroll
        for (int d = 0; d < 17; ++d) sum += src[(r0 + d) * CP + colc];
        for (int ic = r0; ic < r0 + 18; ++ic) {
            if (ic > r0) sum += src[(ic + 16) * CP + colc] - src[(ic - 1) * CP + colc];
            int giR = Lr0 + ic;
            float cyw = (float)(min(giR + RAD, HH - 1) - max(giR - RAD, 0) + 1);
            dst[ic * CP + colc] = sum / (cxw * cyw);
        }
    }
    __syncthreads();

    // phase 4: bilinear upsample from LDS + fuse with hr_x (verbatim passing math)
    {
        int col4 = tid & 31;                 // float4 column in tile
        int rb   = tid >> 5;                 // 0..7
        int J4 = (J0 >> 2) + col4;
        int Jp = J4 << 2;
        const float scale = 255.0f / 1023.0f;
        int xb = (int)((float)Jp * scale);
        int i1 = min(xb + 1, WW - 1), i2 = min(xb + 2, WW - 1);
        int lxb = xb - Lc0, li1 = i1 - Lc0, li2 = i2 - Lc0;   // in [0,35]
        float wxv[4]; bool hs[4];
        #pragma unroll
        for (int k = 0; k < 4; k++) {
            float xsk = (float)(Jp + k) * scale;
            int x0 = (int)xsk;
            wxv[k] = xsk - (float)x0;
            hs[k] = (x0 > xb);
        }
        const float4* h4 = (const float4*)hrx;
        float4* o4 = (float4*)out;
        int planeHR = p * 262144;            // 1024*256 float4 per plane
        #pragma unroll
        for (int it = 0; it < 16; ++it) {
            int row = (it << 3) + rb;        // 0..127
            int I = I0 + row;
            float ysf = (float)I * scale;
            int y0 = (int)ysf;
            float wy = ysf - (float)y0;
            int y1 = min(y0 + 1, HH - 1);
            int ly0 = y0 - Lr0, ly1 = y1 - Lr0;   // in [0,35]
            const float* a0p = mAb + ly0 * CP;
            const float* a1p = mAb + ly1 * CP;
            const float* b0p = mBb + ly0 * CP;
            const float* b1p = mBb + ly1 * CP;
            float A0a = a0p[lxb], A0b = a0p[li1], A0c = a0p[li2];
            float A1a = a1p[lxb], A1b = a1p[li1], A1c = a1p[li2];
            float B0a = b0p[lxb], B0b = b0p[li1], B0c = b0p[li2];
            float B1a = b1p[lxb], B1b = b1p[li1], B1c = b1p[li2];
            int hidx = planeHR + I * 256 + J4;
            float4 h = h4[hidx];
            float hv[4] = {h.x, h.y, h.z, h.w};
            float ov[4];
            float omwy = 1.0f - wy;
            #pragma unroll
            for (int k = 0; k < 4; k++) {
                bool hb = hs[k];
                float Alo0 = hb ? A0b : A0a, Ahi0 = hb ? A0c : A0b;
                float Alo1 = hb ? A1b : A1a, Ahi1 = hb ? A1c : A1b;
                float Blo0 = hb ? B0b : B0a, Bhi0 = hb ? B0c : B0b;
                float Blo1 = hb ? B1b : B1a, Bhi1 = hb ? B1c : B1b;
                float wx = wxv[k], omwx = 1.0f - wx;
                float Ar0 = Alo0 * omwx + Ahi0 * wx;
                float Ar1 = Alo1 * omwx + Ahi1 * wx;
                float Br0 = Blo0 * omwx + Bhi0 * wx;
                float Br1 = Blo1 * omwx + Bhi1 * wx;
                float Avv = Ar0 * omwy + Ar1 * wy;
                float Bvv = Br0 * omwy + Br1 * wy;
                ov[k] = Avv * hv[k] + Bvv;
            }
            float4 o; o.x = ov[0]; o.y = ov[1]; o.z = ov[2]; o.w = ov[3];
            o4[hidx] = o;
        }
    }
}

extern "C" void kernel_launch(void* const* d_in, const int* in_sizes, int n_in,
                              void* d_out, int out_size, void* d_ws, size_t ws_size,
                              hipStream_t stream) {
    const float* lr_x = (const float*)d_in[0];
    const float* lr_y = (const float*)d_in[1];
    const float* hr_x = (const float*)d_in[2];
    const float* l_a  = (const float*)d_in[3];
    float* out = (float*)d_out;

    float* ws       = (float*)d_ws;
    float* partials = ws;                 // 96 floats (pad to 256)
    float* Ab       = ws + 256;
    float* Bb       = Ab + NC * PS;

    k_reduce<<<96, 256, 0, stream>>>(l_a, partials);
    k_ab    <<<576, 256, 0, stream>>>(l_a, lr_x, lr_y, partials, Ab, Bb);
    k_tile  <<<768, 256, 0, stream>>>(Ab, Bb, hr_x, out);
}

// Round 6
// 138.056 us; speedup vs baseline: 1.1767x; 1.0096x over previous
//
#include <hip/hip_runtime.h>

// Resubmission of the round-4-derived 64x64-tile version (round-5 bench died to
// container-infra flake, as in round 2; round-3-style re-issue).

#define RAD 8
#define HH 256
#define WW 256
#define NC 12
#define PS (HH*WW)
#define SCALE (255.0f/1023.0f)

// ---- k_tile geometry (64x64 HR tile) ----
#define NA2 36      // A/B halo tile rows/cols (20 center + 8 halo each side)
#define NC2 20      // center rows/cols (18 exact + 2 slack)
#define AP2 37      // LDS stride for A/B tile (37%32=5, conflict-free)
#define HP2 21      // LDS stride for H-boxed / final tiles (21%32=21)

__device__ __forceinline__ int swz3072(int b) { return (b & 7) * 384 + (b >> 3); }
__device__ __forceinline__ int swz1152(int b) { return (b & 7) * 144 + (b >> 3); }

// run17: lane l returns sum of x over lanes [l-16, l] (valid for l >= 16).
__device__ __forceinline__ float run17(float x) {
    float s = x + __shfl_up(x, 1, 64);
    s += __shfl_up(s, 2, 64);
    s += __shfl_up(s, 4, 64);
    s += __shfl_up(s, 8, 64);      // sum of lanes [l-15, l]
    s += __shfl_up(x, 16, 64);     // + lane l-16 -> 17-wide
    return s;
}

// ---------- K0: global sum of |l_a|+eps ----------
__global__ __launch_bounds__(256) void k_reduce(const float* __restrict__ la,
                                                float* __restrict__ partials) {
    int tid = threadIdx.x;
    __shared__ float ls[4];
    const float4* p4 = (const float4*)la;
    int base = blockIdx.x * 2048 + tid;
    float s = 0.f;
    #pragma unroll
    for (int i = 0; i < 8; i++) {
        float4 v = p4[base + i * 256];
        s += (fabsf(v.x) + 1e-12f) + (fabsf(v.y) + 1e-12f) +
             (fabsf(v.z) + 1e-12f) + (fabsf(v.w) + 1e-12f);
    }
    for (int off = 32; off > 0; off >>= 1) s += __shfl_down(s, off, 64);
    int lane = tid & 63, wid = tid >> 6;
    if (lane == 0) ls[wid] = s;
    __syncthreads();
    if (tid == 0) partials[blockIdx.x] = ls[0] + ls[1] + ls[2] + ls[3];
}

// ---------- K1: A,b once per LR pixel. Wave = 48-col x 4-row patch ----------
__global__ __launch_bounds__(256) void k_ab(const float* __restrict__ la,
                                            const float* __restrict__ lx,
                                            const float* __restrict__ ly,
                                            const float* __restrict__ partials,
                                            float* __restrict__ Ab,
                                            float* __restrict__ Bb) {
    int tid = threadIdx.x, lane = tid & 63, wv = tid >> 6;
    int gw = swz1152(blockIdx.x) * 4 + wv;       // 0..4607
    int p  = gw / 384;
    int r  = gw - p * 384;
    int s  = r >> 6;                             // col strip 0..5
    int bd = r & 63;                             // row band 0..63
    int i0 = bd << 2;                            // first output row (4-row band)
    int C0 = s * 48;
    int col = C0 - 8 + lane;                     // product column
    bool vc = (col >= 0) && (col < WW);
    int colc = min(max(col, 0), WW - 1);
    const float* pa = la + p * PS + colc;
    const float* px = lx + p * PS + colc;
    const float* py = ly + p * PS + colc;

    // invS from the 96 per-block partials (wave-local, no barrier)
    float psum = partials[lane] + ((lane < 32) ? partials[lane + 64] : 0.0f);
    #pragma unroll
    for (int off = 32; off > 0; off >>= 1) psum += __shfl_xor(psum, off, 64);
    float invS = 1.0f / psum;

    int  cA  = C0 - 16 + lane;                   // output center col
    bool vcA = (lane >= 16) && (cA < WW);
    float cxA = (float)(min(cA + RAD, WW - 1) - max(cA - RAD, 0) + 1);

    float s0 = 0, s1 = 0, s2 = 0, s3 = 0, s4 = 0, s5 = 0;
    auto accum = [&](int rr, float sg) {
        float va = 0.f, vx = 0.f, vy = 0.f;
        if (vc) { int o = rr * WW; va = pa[o]; vx = px[o]; vy = py[o]; }
        float a  = vc ? (fabsf(va) + 1e-12f) : 0.f;   // exact 0 outside image
        float ax = a * vx, ay = a * vy;
        s0 = fmaf(sg, a, s0); s1 = fmaf(sg, ax, s1); s2 = fmaf(sg, ay, s2);
        s3 = fmaf(sg, a * ax, s3); s4 = fmaf(sg, ax * ax, s4); s5 = fmaf(sg, ax * ay, s5);
    };

    // warm-up vertical window rows [i0-8, i0+8]
    #pragma unroll
    for (int d = -8; d <= 8; ++d) {
        int rr = i0 + d;
        if (rr >= 0 && rr < HH) accum(rr, 1.0f);
    }

    float* Apl = Ab + p * PS;
    float* Bpl = Bb + p * PS;
    #pragma unroll
    for (int k = 0; k < 4; ++k) {
        int m = i0 + k;                          // in [0,255]
        if (k > 0) {
            int ra = m + 8; if (ra < HH) accum(ra, 1.0f);
            int rs = m - 9; if (rs >= 0) accum(rs, -1.0f);
        }
        float h0 = run17(s0), h1 = run17(s1), h2 = run17(s2),
              h3 = run17(s3), h4 = run17(s4), h5 = run17(s5);
        float cy = (float)(min(m + RAD, HH - 1) - max(m - RAD, 0) + 1);
        float Nv = cxA * cy, invN = 1.0f / Nv;
        float m_a = h0 * invN, m_ax = h1 * invN, m_ay = h2 * invN;
        float m_tax = h3 * invN * invS;
        float m_a2x2 = h4 * invN, m_a2xy = h5 * invN;
        float tempv = fabsf(m_a2x2 - Nv * m_tax * m_ax);
        float Av = (m_a2xy - Nv * m_tax * m_ay) / (tempv + 1e-8f);
        float bv = (m_ay - Av * m_ax) / m_a;
        if (vcA) {
            int o = m * WW + cA;
            Apl[o] = Av;
            Bpl[o] = bv;
        }
    }
}

// ---------- K2: per-64x64-HR-tile: box(A),box(b)/N in LDS + bilinear resize + fuse ----------
// 3072 blocks, 256 threads, 16.7 KB LDS -> 8 blocks/CU (32 waves/CU).
__global__ __launch_bounds__(256) void k_tile(const float* __restrict__ Ab,
                                              const float* __restrict__ Bb,
                                              const float* __restrict__ hrx,
                                              float* __restrict__ out) {
    __shared__ float sA[NA2 * AP2], sB[NA2 * AP2];   // 36x36 A/B halo tiles
    __shared__ float sHA[NA2 * HP2], sHB[NA2 * HP2]; // H-boxed [36][20]
    float* mAb = sA;                                 // alias: sA/sB dead after phase 2
    float* mBb = sB;

    int tid = threadIdx.x;
    int b  = swz3072(blockIdx.x);
    int p  = b >> 8;                 // plane 0..11
    int t  = b & 255;
    int ti = t >> 4, tj = t & 15;    // 16x16 tiles of 64x64
    int I0 = ti << 6, J0 = tj << 6;
    int Lr0 = max(0, (I0 * 255) / 1023 - 1);
    int Lc0 = max(0, (J0 * 255) / 1023 - 1);

    // phase 1: load 36x36 A/B region, zero-padded outside image
    const float* Apl = Ab + p * PS;
    const float* Bpl = Bb + p * PS;
    for (int idx = tid; idx < NA2 * NA2; idx += 256) {
        int r = idx / NA2, c = idx - r * NA2;
        int gr = Lr0 - 8 + r, gc = Lc0 - 8 + c;
        float av = 0.f, bv = 0.f;
        if (gr >= 0 && gr < HH && gc >= 0 && gc < WW) {
            int o = gr * WW + gc;
            av = Apl[o]; bv = Bpl[o];
        }
        sA[r * AP2 + c] = av;
        sB[r * AP2 + c] = bv;
    }
    __syncthreads();

    // phase 2: horizontal 17-tap (direct, fully parallel) -> sHA/sHB [36][20]
    for (int job = tid; job < 2 * NA2 * NC2; job += 256) {
        int which = (job >= NA2 * NC2);
        int rest  = which ? job - NA2 * NC2 : job;
        int r = rest / NC2, c = rest - r * NC2;
        const float* rp = (which ? sB : sA) + r * AP2 + c;
        float s = 0.f;
        #pragma unroll
        for (int j = 0; j < 17; ++j) s += rp[j];
        (which ? sHB : sHA)[r * HP2 + c] = s;
    }
    __syncthreads();

    // phase 3: vertical 17-tap + /N -> mAb/mBb [20][21] (alias over sA/sB)
    for (int job = tid; job < 2 * NC2 * NC2; job += 256) {
        int which = (job >= NC2 * NC2);
        int rest  = which ? job - NC2 * NC2 : job;
        int r = rest / NC2, c = rest - r * NC2;
        const float* sp = (which ? sHB : sHA) + r * HP2 + c;
        float s = 0.f;
        #pragma unroll
        for (int j = 0; j < 17; ++j) s += sp[j * HP2];
        int gj = Lc0 + c, gi = Lr0 + r;
        float cxw = (float)(min(gj + RAD, WW - 1) - max(gj - RAD, 0) + 1);
        float cyw = (float)(min(gi + RAD, HH - 1) - max(gi - RAD, 0) + 1);
        (which ? mBb : mAb)[r * HP2 + c] = s / (cxw * cyw);
    }
    __syncthreads();

    // phase 4: bilinear upsample from LDS + fuse with hr_x (verbatim passing math;
    // all 4 hr_x float4 loads issued up front for 4-deep per-lane MLP)
    {
        int col4 = tid & 15;                 // float4 column in 64-wide tile
        int rg   = tid >> 4;                 // 0..15 row group
        int J4 = (J0 >> 2) + col4;
        int Jp = J4 << 2;
        int xb = (int)((float)Jp * SCALE);
        int i1 = min(xb + 1, WW - 1), i2 = min(xb + 2, WW - 1);
        int lxb = xb - Lc0, li1 = i1 - Lc0, li2 = i2 - Lc0;   // in [0,19]
        float wxv[4]; bool hs[4];
        #pragma unroll
        for (int k = 0; k < 4; k++) {
            float xsk = (float)(Jp + k) * SCALE;
            int x0 = (int)xsk;
            wxv[k] = xsk - (float)x0;
            hs[k] = (x0 > xb);
        }
        const float4* h4 = (const float4*)hrx;
        float4* o4 = (float4*)out;
        int planeHR = p * 262144;            // 1024*256 float4 per plane

        int hidx0 = planeHR + (I0 + 0 * 16 + rg) * 256 + J4;
        int hidx1 = planeHR + (I0 + 1 * 16 + rg) * 256 + J4;
        int hidx2 = planeHR + (I0 + 2 * 16 + rg) * 256 + J4;
        int hidx3 = planeHR + (I0 + 3 * 16 + rg) * 256 + J4;
        float4 hp0 = h4[hidx0], hp1 = h4[hidx1], hp2 = h4[hidx2], hp3 = h4[hidx3];

        #pragma unroll
        for (int it = 0; it < 4; ++it) {
            int row = (it << 4) + rg;        // 0..63
            int I = I0 + row;
            float ysf = (float)I * SCALE;
            int y0 = (int)ysf;
            float wy = ysf - (float)y0;
            int y1 = min(y0 + 1, HH - 1);
            int ly0 = y0 - Lr0, ly1 = y1 - Lr0;   // in [0,19]
            const float* a0p = mAb + ly0 * HP2;
            const float* a1p = mAb + ly1 * HP2;
            const float* b0p = mBb + ly0 * HP2;
            const float* b1p = mBb + ly1 * HP2;
            float A0a = a0p[lxb], A0b = a0p[li1], A0c = a0p[li2];
            float A1a = a1p[lxb], A1b = a1p[li1], A1c = a1p[li2];
            float B0a = b0p[lxb], B0b = b0p[li1], B0c = b0p[li2];
            float B1a = b1p[lxb], B1b = b1p[li1], B1c = b1p[li2];
            float4 h = (it == 0) ? hp0 : (it == 1) ? hp1 : (it == 2) ? hp2 : hp3;
            int hidx = (it == 0) ? hidx0 : (it == 1) ? hidx1 : (it == 2) ? hidx2 : hidx3;
            float hv[4] = {h.x, h.y, h.z, h.w};
            float ov[4];
            float omwy = 1.0f - wy;
            #pragma unroll
            for (int k = 0; k < 4; k++) {
                bool hb = hs[k];
                float Alo0 = hb ? A0b : A0a, Ahi0 = hb ? A0c : A0b;
                float Alo1 = hb ? A1b : A1a, Ahi1 = hb ? A1c : A1b;
                float Blo0 = hb ? B0b : B0a, Bhi0 = hb ? B0c : B0b;
                float Blo1 = hb ? B1b : B1a, Bhi1 = hb ? B1c : B1b;
                float wx = wxv[k], omwx = 1.0f - wx;
                float Ar0 = Alo0 * omwx + Ahi0 * wx;
                float Ar1 = Alo1 * omwx + Ahi1 * wx;
                float Br0 = Blo0 * omwx + Bhi0 * wx;
                float Br1 = Blo1 * omwx + Bhi1 * wx;
                float Avv = Ar0 * omwy + Ar1 * wy;
                float Bvv = Br0 * omwy + Br1 * wy;
                ov[k] = Avv * hv[k] + Bvv;
            }
            float4 o; o.x = ov[0]; o.y = ov[1]; o.z = ov[2]; o.w = ov[3];
            o4[hidx] = o;
        }
    }
}

extern "C" void kernel_launch(void* const* d_in, const int* in_sizes, int n_in,
                              void* d_out, int out_size, void* d_ws, size_t ws_size,
                              hipStream_t stream) {
    const float* lr_x = (const float*)d_in[0];
    const float* lr_y = (const float*)d_in[1];
    const float* hr_x = (const float*)d_in[2];
    const float* l_a  = (const float*)d_in[3];
    float* out = (float*)d_out;

    float* ws       = (float*)d_ws;
    float* partials = ws;                 // 96 floats (pad to 256)
    float* Ab       = ws + 256;
    float* Bb       = Ab + NC * PS;

    k_reduce<<<96, 256, 0, stream>>>(l_a, partials);
    k_ab    <<<1152, 256, 0, stream>>>(l_a, lr_x, lr_y, partials, Ab, Bb);
    k_tile  <<<3072, 256, 0, stream>>>(Ab, Bb, hr_x, out);
}